// Round 19
// baseline (234.725 us; speedup 1.0000x reference)
//
#include <hip/hip_runtime.h>
#include <hip/hip_bf16.h>

#define NTOT (4*256*256)      // 262144 feature rows
#define DIM 384
#define KCL 256               // clusters
#define BM 64                 // rows per block tile
#define TBS 256
#define GRID_MAIN (NTOT/BM)   // 4096 blocks
#define NT 12                 // K-steps of 32
#define EPS 1e-12f

// LDS: 4 waves x 8 KiB PRIVATE region: 2 bufs x (hi 2KB | lo 2KB).
#define SMEM_BYTES 32768

typedef __attribute__((ext_vector_type(8))) _Float16 f16x8;
typedef __attribute__((ext_vector_type(4))) float f32x4;

// ---------------------------------------------------------------------------
// Pre-pass (UNCHANGED, proven R9-R18): L2-normalize clusters; fp16 hi+lo in
// FRAGMENT ORDER: (j,d) -> ((((t*4+w)*4+n)*4+g)*16+nl)*8+d0.
// ---------------------------------------------------------------------------
__global__ void prep_clusters(const float* __restrict__ cc,
                              _Float16* __restrict__ bh,
                              _Float16* __restrict__ bl) {
    int j = blockIdx.x, l = threadIdx.x;   // 256 blocks x 64 lanes
    float v[6]; float ssq = 0.f;
#pragma unroll
    for (int i = 0; i < 6; ++i) { v[i] = cc[j*DIM + l + 64*i]; ssq = fmaf(v[i], v[i], ssq); }
#pragma unroll
    for (int off = 32; off >= 1; off >>= 1) ssq += __shfl_xor(ssq, off);
    float inv = 1.f / fmaxf(sqrtf(ssq), EPS);
    const int w = j >> 6, n = (j >> 4) & 3, nl = j & 15;
#pragma unroll
    for (int i = 0; i < 6; ++i) {
        int d = l + 64 * i;
        float x = v[i] * inv;
        _Float16 h  = (_Float16)x;
        _Float16 lo = (_Float16)(x - (float)h);
        size_t idx = (size_t)((((((d >> 5)*4 + w)*4 + n)*4 + ((d >> 3) & 3))*16 + nl)*8
                              + (d & 7));
        bh[idx] = h;
        bl[idx] = lo;
    }
}

// ---------------------------------------------------------------------------
// Main: 3-pass split-fp16 MFMA GEMM, ZERO barriers in the K-loop.
// wave(wv = 2r+c): rows [32r,32r+32) of the block tile, cols [128c,128c+128).
// A: wave-private LDS (8 KiB), same-wave lgkm ordering only.
// B: global->reg, fragment-order, 2 chunks of 4 tiles per step.
// Per-element accumulation order identical to R2-R18 -> bit-exact scores.
// ---------------------------------------------------------------------------
__global__ __launch_bounds__(TBS, 3)
void kmeans_main(const float* __restrict__ A,    // [NTOT][384] f32
                 const float* __restrict__ W,    // [NTOT]
                 const _Float16* __restrict__ Bh,// fragment-order fp16 hi
                 const _Float16* __restrict__ Bl,// fragment-order fp16 lo
                 const int*   __restrict__ PA,   // [256]
                 float* __restrict__ out,        // [2*NTOT+1]
                 float* __restrict__ partial)    // [GRID_MAIN]
{
    __shared__ unsigned char smem[SMEM_BYTES];

    const int tid   = threadIdx.x;
    const int wv    = tid >> 6;
    const int lane  = tid & 63;
    const int g     = lane >> 4;
    const int l15   = lane & 15;
    const int sw    = (l15 >> 1) & 3;   // frag-read swizzle term (proven)
    const int rstrip= wv >> 1;          // 0..1 : row strip
    const int chalf = wv & 1;           // 0..1 : col half
    const int row0  = blockIdx.x * BM + rstrip * 32;

    // A stage mapping: lane -> row (lane>>1) of the 32-row strip, k-half (lane&1)*16
    const int srow = lane >> 1;
    const int shalf= lane & 1;
    const float* ap = A + (size_t)(row0 + srow) * DIM + shalf * 16;

    unsigned char* wbase = smem + wv * 8192;    // private: buf p at +p*4096 (hi), +2048 (lo)
    const int wsw  = (srow >> 1) & 3;
    const int ws0  = (srow * 4 + ((2 * shalf + 0) ^ wsw)) * 16;   // write slot bytes
    const int ws1  = (srow * 4 + ((2 * shalf + 1) ^ wsw)) * 16;
    const int fa   = (l15 * 4 + (g ^ sw)) * 16;                   // frag base (+m*1024)

    // B: wave's 8 tiles = global tiles 8*chalf + (ch*4+i); bsh embeds chalf+lane
    const unsigned char* bsh = (const unsigned char*)Bh + (size_t)(8 * chalf) * 1024 + lane * 16;
    const unsigned char* bsl = (const unsigned char*)Bl + (size_t)(8 * chalf) * 1024 + lane * 16;

    f32x4 acc[2][8];
#pragma unroll
    for (int m = 0; m < 2; ++m)
#pragma unroll
        for (int T = 0; T < 8; ++T) acc[m][T] = (f32x4){0.f, 0.f, 0.f, 0.f};
    float ssq = 0.f;

    float4 sA[2][4];   // raw A parity slots: 16 floats = rows srow, k-half

    auto LDA = [&](int s, int tt) {
#pragma unroll
        for (int q = 0; q < 4; ++q)
            sA[s][q] = *(const float4*)(ap + tt * 32 + q * 4);
    };
    // split 16 f32 -> hi/lo fp16, ssq, 4 ds_writes to private buf p
    auto CVTW = [&](int s, int p) {
        float f[16];
#pragma unroll
        for (int q = 0; q < 4; ++q) {
            f[q*4+0] = sA[s][q].x; f[q*4+1] = sA[s][q].y;
            f[q*4+2] = sA[s][q].z; f[q*4+3] = sA[s][q].w;
        }
        f16x8 h0, h1, l0, l1;
#pragma unroll
        for (int e = 0; e < 8; ++e) {
            _Float16 hh = (_Float16)f[e];
            h0[e] = hh; l0[e] = (_Float16)(f[e] - (float)hh);
            ssq = fmaf(f[e], f[e], ssq);
            _Float16 hh2 = (_Float16)f[8+e];
            h1[e] = hh2; l1[e] = (_Float16)(f[8+e] - (float)hh2);
            ssq = fmaf(f[8+e], f[8+e], ssq);
        }
        *(f16x8*)(wbase + p * 4096 + ws0)        = h0;
        *(f16x8*)(wbase + p * 4096 + ws1)        = h1;
        *(f16x8*)(wbase + p * 4096 + 2048 + ws0) = l0;
        *(f16x8*)(wbase + p * 4096 + 2048 + ws1) = l1;
    };

    // ---- prologue: tiles 0,1 -> raw slots; publish tile0 to buf0 ----
    LDA(0, 0);
    LDA(1, 1);
    CVTW(0, 0);

    // ---- main loop: NO barriers; same-wave lgkm ordering only ----
#pragma unroll
    for (int t = 0; t < NT; ++t) {
        // A fragments of tile t from private buf(t&1)
        f16x8 ahf[2], alf[2];
#pragma unroll
        for (int m = 0; m < 2; ++m) {
            ahf[m] = *(const f16x8*)(wbase + (t & 1) * 4096 + fa + m * 1024);
            alf[m] = *(const f16x8*)(wbase + (t & 1) * 4096 + 2048 + fa + m * 1024);
        }
        if (t + 2 < NT) LDA(t & 1, t + 2);          // slot freed by CVTW(t-1... parity)
        if (t + 1 < NT) CVTW((t + 1) & 1, (t + 1) & 1);

        // 2 B-chunks x (hh, hl, lh) -- per-element order identical to R2-R18
#pragma unroll
        for (int ch = 0; ch < 2; ++ch) {
            f16x8 bfh[4], bfl[4];
#pragma unroll
            for (int i = 0; i < 4; ++i) {
                bfh[i] = *(const f16x8*)(bsh + (size_t)(t * 16 + ch * 4 + i) * 1024);
                bfl[i] = *(const f16x8*)(bsl + (size_t)(t * 16 + ch * 4 + i) * 1024);
            }
#pragma unroll
            for (int m = 0; m < 2; ++m)
#pragma unroll
                for (int i = 0; i < 4; ++i)
                    acc[m][ch*4+i] = __builtin_amdgcn_mfma_f32_16x16x32_f16(ahf[m], bfh[i], acc[m][ch*4+i], 0, 0, 0);
#pragma unroll
            for (int m = 0; m < 2; ++m)
#pragma unroll
                for (int i = 0; i < 4; ++i)
                    acc[m][ch*4+i] = __builtin_amdgcn_mfma_f32_16x16x32_f16(ahf[m], bfl[i], acc[m][ch*4+i], 0, 0, 0);
#pragma unroll
            for (int m = 0; m < 2; ++m)
#pragma unroll
                for (int i = 0; i < 4; ++i)
                    acc[m][ch*4+i] = __builtin_amdgcn_mfma_f32_16x16x32_f16(alf[m], bfh[i], acc[m][ch*4+i], 0, 0, 0);
        }
    }

    // ---- epilogue ----
    float* wvalp  = (float*)smem;                 // [4][32] 512 B
    int*   wcolp  = (int*)(smem + 512);           // [4][32] 512 B
    float* rowssq = (float*)(smem + 1024);        // [64]    256 B
    __syncthreads();   // repurpose smem (all K-loop LDS reads done in-wave)

    // row sumsq: lane pair (srow) -> full row
    ssq += __shfl_xor(ssq, 1);
    if (chalf == 0 && shalf == 0) rowssq[rstrip * 32 + srow] = ssq;

    // per-wave argmax over its 128 cols.
    // acc[m][T][j] = S[row 16m+4g+j][col 128*chalf + 16T + l15]
#pragma unroll
    for (int m = 0; m < 2; ++m) {
#pragma unroll
        for (int j = 0; j < 4; ++j) {
            float best = acc[m][0][j];
            int   bc   = 128 * chalf + l15;
#pragma unroll
            for (int T = 1; T < 8; ++T) {
                float v = acc[m][T][j];
                int   c = 128 * chalf + 16 * T + l15;
                if (v > best) { best = v; bc = c; }
            }
#pragma unroll
            for (int off = 1; off < 16; off <<= 1) {
                float ov = __shfl_xor(best, off);
                int   oc = __shfl_xor(bc, off);
                if (ov > best || (ov == best && oc < bc)) { best = ov; bc = oc; }
            }
            if (l15 == 0) {
                int rl = 16 * m + 4 * g + j;      // 0..31 within strip
                wvalp[wv * 32 + rl] = best;
                wcolp[wv * 32 + rl] = bc;
            }
        }
    }
    __syncthreads();

    // combine col-halves per row; outputs + loss partial
    if (tid < BM) {
        int r = tid;
        int w0 = (r >> 5) * 2;                     // c=0 wave of this strip
        int rl = r & 31;
        float b0 = wvalp[w0 * 32 + rl];      int c0 = wcolp[w0 * 32 + rl];
        float b1 = wvalp[(w0 + 1) * 32 + rl]; int c1 = wcolp[(w0 + 1) * 32 + rl];
        float b = b0; int c = c0;
        if (b1 > b) { b = b1; c = c1; }            // ties keep c0 (lower col)
        float inv = 1.f / fmaxf(sqrtf(rowssq[r]), EPS);
        int gr = blockIdx.x * BM + r;
        out[gr]        = (float)c;
        out[NTOT + gr] = (float)PA[c];
        float lsum = -(b * inv) * W[gr];
#pragma unroll
        for (int off = 32; off >= 1; off >>= 1) lsum += __shfl_xor(lsum, off);
        if (tid == 0) partial[blockIdx.x] = lsum;
    }
}

// ---------------------------------------------------------------------------
// Deterministic final loss reduction: 4096 partials -> mean
// ---------------------------------------------------------------------------
__global__ void loss_reduce(const float* __restrict__ partial, float* __restrict__ out_loss) {
    __shared__ float s[256];
    float v = 0.f;
    for (int i = threadIdx.x; i < GRID_MAIN; i += 256) v += partial[i];
    s[threadIdx.x] = v;
    __syncthreads();
    for (int off = 128; off >= 1; off >>= 1) {
        if ((int)threadIdx.x < off) s[threadIdx.x] += s[threadIdx.x + off];
        __syncthreads();
    }
    if (threadIdx.x == 0) out_loss[0] = s[0] * (1.0f / (float)NTOT);
}

extern "C" void kernel_launch(void* const* d_in, const int* in_sizes, int n_in,
                              void* d_out, int out_size, void* d_ws, size_t ws_size,
                              hipStream_t stream) {
    const float* features = (const float*)d_in[0];
    const float* weight   = (const float*)d_in[1];
    const float* cc       = (const float*)d_in[2];
    const int*   pa       = (const int*)d_in[3];
    float* out = (float*)d_out;

    _Float16* bh   = (_Float16*)d_ws;              // 192 KiB fragment-order hi
    _Float16* bl   = bh + KCL * DIM;               // 192 KiB fragment-order lo
    float* partial = (float*)(bl + KCL * DIM);     // 16 KiB

    hipLaunchKernelGGL(prep_clusters, dim3(KCL), dim3(64), 0, stream, cc, bh, bl);
    hipLaunchKernelGGL(kmeans_main, dim3(GRID_MAIN), dim3(TBS), 0, stream,
                       features, weight, bh, bl, pa, out, partial);
    hipLaunchKernelGGL(loss_reduce, dim3(1), dim3(256), 0, stream, partial, out + 2 * NTOT);
}